// Round 3
// 996.360 us; speedup vs baseline: 1.0413x; 1.0413x over previous
//
#include <hip/hip_runtime.h>
#include <cstdint>
#include <cstddef>

// ---------------------------------------------------------------------------
// HiERABlock, MI355X.  Dtype-adaptive (fp32/bf16 inputs, flag sniffed on
// device).  Internal pipeline all bf16, "windowed row order".
// GEMMs: 256xBN-tile 8-wave BK=64 double-buffered pipeline (HK/m201-style):
//   T2 XOR-swizzled LDS (pre-swizzled global source for global_load_lds),
//   T3/T4 cross-barrier staging with a single vmcnt(0)+s_barrier per K-tile
//   (raw barriers only -- no __syncthreads in the main loop),
//   T5 setprio around MFMA clusters, T1 XCD blockIdx swizzle.
// LDS is STATIC __shared__ (128KB / 96KB).  NOTE: no braced-init arrays of
// LDS pointers (clang folds those to unsupported static addrspacecast
// initializers) -- double-buffer pointers are computed per iteration.
// BN=256 for qkv/fc1, BN=128 for N=768 GEMMs (proj/fc2) for dispatch-tail.
// EPI 0: bf16 out; EPI 1: layerscale residual RMW (coalesced); EPI 2: GELU.
// ---------------------------------------------------------------------------

typedef unsigned short u16;
typedef short short8 __attribute__((ext_vector_type(8)));
typedef float floatx4 __attribute__((ext_vector_type(4)));

static __device__ __forceinline__ float bf2f(u16 u) {
  return __uint_as_float(((unsigned)u) << 16);
}
static __device__ __forceinline__ u16 f2bf(float f) {
  unsigned u = __float_as_uint(f);
  return (u16)((u + 0x7FFFu + ((u >> 16) & 1u)) >> 16);
}
static __device__ __forceinline__ float ldin(const void* p, size_t i, int isf) {
  return isf ? ((const float*)p)[i] : bf2f(((const u16*)p)[i]);
}
static __device__ __forceinline__ void gload_lds16(const void* g, void* l) {
  __builtin_amdgcn_global_load_lds(
      (const __attribute__((address_space(1))) void*)g,
      (__attribute__((address_space(3))) void*)l, 16, 0, 0);
}
// tanh-form GELU: max |err| ~3e-4; downstream effect ~1e-9 (gamma2=1e-5)
static __device__ __forceinline__ float fast_gelu(float v) {
  float u2 = v * (1.5957691216f + 0.0713548163f * v * v);
  return v * (1.0f / (1.0f + __expf(-u2)));
}

// ---- dtype detector --------------------------------------------------------
__global__ __launch_bounds__(256) void detect_kernel(const u16* __restrict__ x,
                                                     int* __restrict__ flag) {
  __shared__ int tot;
  if (threadIdx.x == 0) tot = 0;
  __syncthreads();
  int cnt = 0;
  for (int i = threadIdx.x; i < 4096; i += 256) {
    int e = (x[i] >> 7) & 0xFF;
    if (e >= 0xC1) cnt++;
  }
  atomicAdd(&tot, cnt);
  __syncthreads();
  if (threadIdx.x == 0) flag[0] = (tot > 16) ? 1 : 0;
}

// ---- convert small params to bf16 ------------------------------------------
__global__ __launch_bounds__(256) void cvt_params_kernel(
    const void* n1w, const void* n1b, const void* qkvb, const void* projb,
    const void* n2w, const void* n2b, const void* fc1b, const void* fc2b,
    const void* g1, const void* g2, const void* bt, u16* __restrict__ P,
    const int* __restrict__ flag) {
  int isf = *flag;
  int i = blockIdx.x * 256 + threadIdx.x;
  const void* src; int off;
  if      (i < 768)   { src = n1w;   off = i; }
  else if (i < 1536)  { src = n1b;   off = i - 768; }
  else if (i < 3840)  { src = qkvb;  off = i - 1536; }
  else if (i < 4608)  { src = projb; off = i - 3840; }
  else if (i < 5376)  { src = n2w;   off = i - 4608; }
  else if (i < 6144)  { src = n2b;   off = i - 5376; }
  else if (i < 9216)  { src = fc1b;  off = i - 6144; }
  else if (i < 9984)  { src = fc2b;  off = i - 9216; }
  else if (i < 10752) { src = g1;    off = i - 9984; }
  else if (i < 11520) { src = g2;    off = i - 10752; }
  else if (i < 20268) { src = bt;    off = i - 11520; }
  else return;
  P[i] = f2bf(ldin(src, off, isf));
}

// ---- weight transpose ------------------------------------------------------
__global__ __launch_bounds__(256) void wtr_kernel(const void* __restrict__ W,
                                                  u16* __restrict__ WT,
                                                  int K, int N,
                                                  const int* __restrict__ flag) {
  int isf = *flag;
  __shared__ u16 tl[32][33];
  int tx = threadIdx.x, ty = threadIdx.y;
  int n0 = blockIdx.x * 32, k0 = blockIdx.y * 32;
#pragma unroll
  for (int j = 0; j < 32; j += 8)
    tl[ty + j][tx] = f2bf(ldin(W, (size_t)(k0 + ty + j) * N + n0 + tx, isf));
  __syncthreads();
#pragma unroll
  for (int j = 0; j < 32; j += 8)
    WT[(size_t)(n0 + ty + j) * K + k0 + tx] = tl[tx][ty + j];
}

// ---- input permute ---------------------------------------------------------
__global__ __launch_bounds__(256) void tin_kernel(const void* __restrict__ x,
                                                  u16* __restrict__ sc,
                                                  const int* __restrict__ flag) {
  int isf = *flag;
  int cc = blockIdx.x, h = blockIdx.y, b = blockIdx.z;  // grid (12,56,8)
  __shared__ u16 tile[64 * 57];
  int tid = threadIdx.x;
  for (int i = tid; i < 64 * 56; i += 256) {
    int ci = i / 56, w = i - ci * 56;
    tile[ci * 57 + w] =
        f2bf(ldin(x, (((size_t)b * 768 + cc * 64 + ci) * 56 + h) * 56 + w, isf));
  }
  __syncthreads();
  int hb = h / 14, hi = h - hb * 14;
  for (int i = tid; i < 56 * 64; i += 256) {
    int w = i >> 6, ci = i & 63;
    int wb = w / 14, wj = w - wb * 14;
    int r = (b * 16 + hb * 4 + wb) * 196 + hi * 14 + wj;
    sc[(size_t)r * 768 + cc * 64 + ci] = tile[ci * 57 + w];
  }
}

// ---- output permute --------------------------------------------------------
__global__ __launch_bounds__(256) void tout_kernel(const u16* __restrict__ src,
                                                   void* __restrict__ out,
                                                   const int* __restrict__ flag) {
  int isf = *flag;
  int cc = blockIdx.x, h = blockIdx.y, b = blockIdx.z;
  __shared__ u16 tile[64 * 57];
  int tid = threadIdx.x;
  int hb = h / 14, hi = h - hb * 14;
  for (int i = tid; i < 56 * 64; i += 256) {
    int w = i >> 6, ci = i & 63;
    int wb = w / 14, wj = w - wb * 14;
    int r = (b * 16 + hb * 4 + wb) * 196 + hi * 14 + wj;
    tile[ci * 57 + w] = src[(size_t)r * 768 + cc * 64 + ci];
  }
  __syncthreads();
  for (int i = tid; i < 64 * 56; i += 256) {
    int ci = i / 56, w = i - ci * 56;
    size_t o = (((size_t)b * 768 + cc * 64 + ci) * 56 + h) * 56 + w;
    if (isf) ((float*)out)[o] = bf2f(tile[ci * 57 + w]);
    else     ((u16*)out)[o]   = tile[ci * 57 + w];
  }
}

// ---- LayerNorm over C=768 --------------------------------------------------
__global__ __launch_bounds__(256) void ln_kernel(const u16* __restrict__ xin,
                                                 const u16* __restrict__ wt,
                                                 const u16* __restrict__ bs,
                                                 u16* __restrict__ out) {
  int row = blockIdx.x, t = threadIdx.x;
  const u16* xr = xin + (size_t)row * 768;
  float v0 = bf2f(xr[t]), v1 = bf2f(xr[t + 256]), v2 = bf2f(xr[t + 512]);
  float s1 = v0 + v1 + v2;
  float s2 = v0 * v0 + v1 * v1 + v2 * v2;
#pragma unroll
  for (int off = 32; off > 0; off >>= 1) {
    s1 += __shfl_xor(s1, off);
    s2 += __shfl_xor(s2, off);
  }
  __shared__ float p1[4], p2[4];
  if ((t & 63) == 0) { p1[t >> 6] = s1; p2[t >> 6] = s2; }
  __syncthreads();
  float S1 = p1[0] + p1[1] + p1[2] + p1[3];
  float S2 = p2[0] + p2[1] + p2[2] + p2[3];
  float mu = S1 * (1.f / 768.f);
  float var = S2 * (1.f / 768.f) - mu * mu;
  float rs = rsqrtf(var + 1e-5f);
  u16* orow = out + (size_t)row * 768;
  orow[t]       = f2bf((v0 - mu) * rs * bf2f(wt[t])       + bf2f(bs[t]));
  orow[t + 256] = f2bf((v1 - mu) * rs * bf2f(wt[t + 256]) + bf2f(bs[t + 256]));
  orow[t + 512] = f2bf((v2 - mu) * rs * bf2f(wt[t + 512]) + bf2f(bs[t + 512]));
}

// ---------------------------------------------------------------------------
// Pipelined 256xBN GEMM.  NPH=4 -> BN=256 (2x4 waves, 4 phases/K-tile);
// NPH=2 -> BN=128 (4x2 waves, 2 phases/K-tile).  BK=64.
// STATIC LDS (u16): A[2][256][64] then B[2][BN][64], XOR-swizzled:
//   physical 16B slot within a 128B row = logical_slot ^ (row & 7).
// Staging: global_load_lds writes linearly (base + lane*16B); the per-lane
// GLOBAL source address carries the inverse swizzle (rule #21).
// Main loop per K-tile t: {vmcnt(0); s_barrier} (only tile-t loads are
// outstanding -> exact counted wait), then NPH phases of
// {ds_read frags | issue next-tile gload_lds | s_barrier | setprio(1)
//  16 MFMA setprio(0) | s_barrier}.  Loads for t+1 stay in flight across
// all intra-tile barriers (T4).  Epilogue aliases LDS for the C-repack.
// ---------------------------------------------------------------------------
template <int EPI, int NPH>
__global__ __launch_bounds__(512, 2) void gemm256_kernel(
    const u16* __restrict__ A, const u16* __restrict__ BT,
    const u16* __restrict__ bias, const u16* __restrict__ gamma,
    u16* __restrict__ out, int M, int N, int K, int NX, int NYT) {
  constexpr int BN  = 64 * NPH;      // 256 or 128
  constexpr int WM  = 8 / NPH;       // waves along M
  constexpr int MF  = 2 * NPH;       // m-fragments per wave
  constexpr int ATS = 16384;         // A K-tile size in u16 (256*64)
  constexpr int BTS = 4096 * NPH;    // B K-tile size in u16 (BN*64)
  __shared__ __align__(16) u16 LDS[2 * ATS + 2 * BTS];  // 128KB / 96KB static

  int bid = blockIdx.x;
  int r8 = bid & 7, q = bid >> 3;           // T1: XCD swizzle
  int xb = q % NX, yb = (q / NX) * 8 + r8;
  if (yb >= NYT) return;
  int m0 = yb * 256, n0 = xb * BN;

  int tid = threadIdx.x;
  int w = tid >> 6, l = tid & 63;
  int l15 = l & 15, quad = l >> 4;
  int wm = w & (WM - 1), wn = w / WM;

  // staging source pointers (pre-swizzled k offset)
  int lrow8 = l >> 3;                       // 0..7 = row within 8-row segment
  int lk = ((l & 7) ^ lrow8) * 8;           // swizzled k element offset
  const u16* aptr[4];
  const u16* bptr[NPH];
#pragma unroll
  for (int j = 0; j < 4; ++j) {
    int ra = m0 + w * 32 + j * 8 + lrow8;
    if (ra > M - 1) ra = M - 1;             // M-tail clamp (stores guarded)
    aptr[j] = A + (size_t)ra * K + lk;
  }
#pragma unroll
  for (int j = 0; j < NPH; ++j) {
    int rb = n0 + (w * NPH + j) * 8 + lrow8;
    bptr[j] = BT + (size_t)rb * K + lk;
  }
  // fragment-read swizzled in-row offsets (u16 units), kk = 0 / 1
  int kq0 = (((quad * 16)      ^ ((l15 & 7) << 4)) >> 1);
  int kq1 = (((64 + quad * 16) ^ ((l15 & 7) << 4)) >> 1);

  floatx4 acc[MF][4];
#pragma unroll
  for (int i = 0; i < MF; ++i)
#pragma unroll
    for (int jn = 0; jn < 4; ++jn)
#pragma unroll
      for (int e = 0; e < 4; ++e) acc[i][jn][e] = 0.f;

  int nt = K >> 6;
  // prologue: stage K-tile 0 into buffer 0
#pragma unroll
  for (int j = 0; j < 4; ++j)
    gload_lds16(aptr[j], LDS + (w * 4 + j) * 512);
#pragma unroll
  for (int j = 0; j < NPH; ++j)
    gload_lds16(bptr[j], LDS + 2 * ATS + (w * NPH + j) * 512);

  for (int t = 0; t < nt; ++t) {
    // double-buffer pointers computed per iteration (no LDS-ptr arrays!)
    int cur = t & 1, nxt = cur ^ 1;
    const u16* Ac = LDS + cur * ATS;
    const u16* Bc = LDS + 2 * ATS + cur * BTS;
    u16* An = LDS + nxt * ATS;
    u16* Bn = LDS + 2 * ATS + nxt * BTS;
    bool pf = (t + 1) < nt;
    int ko = (t + 1) << 6;
    // only tile-t's loads are outstanding here -> exact counted wait
    asm volatile("s_waitcnt vmcnt(0)" ::: "memory");
    __builtin_amdgcn_s_barrier();
    short8 bfr[4][2];
#pragma unroll
    for (int p = 0; p < NPH; ++p) {
      if (p == 0) {
#pragma unroll
        for (int ni = 0; ni < 4; ++ni) {
          const u16* bp = Bc + (wn * 64 + ni * 16 + l15) * 64;
          bfr[ni][0] = *(const short8*)(bp + kq0);
          bfr[ni][1] = *(const short8*)(bp + kq1);
        }
      }
      short8 af0[2], af1[2];
      {
        const u16* ap0 = Ac + (wm * (32 * NPH) + (2 * p) * 16 + l15) * 64;
        const u16* ap1 = ap0 + 16 * 64;
        af0[0] = *(const short8*)(ap0 + kq0);
        af0[1] = *(const short8*)(ap0 + kq1);
        af1[0] = *(const short8*)(ap1 + kq0);
        af1[1] = *(const short8*)(ap1 + kq1);
      }
      if (pf) {  // stage tile t+1 into the other buffer (stays in flight)
        if constexpr (NPH == 4) {
          gload_lds16(aptr[p] + ko, An + (w * 4 + p) * 512);
          gload_lds16(bptr[p] + ko, Bn + (w * 4 + p) * 512);
        } else {
          gload_lds16(aptr[2 * p] + ko,     An + (w * 4 + 2 * p) * 512);
          gload_lds16(aptr[2 * p + 1] + ko, An + (w * 4 + 2 * p + 1) * 512);
          gload_lds16(bptr[p] + ko,         Bn + (w * 2 + p) * 512);
        }
      }
      __builtin_amdgcn_s_barrier();
      __builtin_amdgcn_s_setprio(1);
#pragma unroll
      for (int ni = 0; ni < 4; ++ni) {
        acc[2 * p][ni] = __builtin_amdgcn_mfma_f32_16x16x32_bf16(
            af0[0], bfr[ni][0], acc[2 * p][ni], 0, 0, 0);
        acc[2 * p][ni] = __builtin_amdgcn_mfma_f32_16x16x32_bf16(
            af0[1], bfr[ni][1], acc[2 * p][ni], 0, 0, 0);
        acc[2 * p + 1][ni] = __builtin_amdgcn_mfma_f32_16x16x32_bf16(
            af1[0], bfr[ni][0], acc[2 * p + 1][ni], 0, 0, 0);
        acc[2 * p + 1][ni] = __builtin_amdgcn_mfma_f32_16x16x32_bf16(
            af1[1], bfr[ni][1], acc[2 * p + 1][ni], 0, 0, 0);
      }
      __builtin_amdgcn_s_setprio(0);
      __builtin_amdgcn_s_barrier();
    }
  }

  // ---- epilogue: repack C tile through LDS (aliases A/B buffers), coalesced
  constexpr int CSTR = BN + 8;
  u16* Cs = LDS;
  float bv[4];
#pragma unroll
  for (int ni = 0; ni < 4; ++ni)
    bv[ni] = bf2f(bias[n0 + wn * 64 + ni * 16 + l15]);
  for (int cch = 0; cch < 2; ++cch) {       // two 128-row chunks of the tile
    __syncthreads();
    if (((wm * NPH) >> 2) == cch) {
      int rbase = wm * (32 * NPH) - cch * 128 + quad * 4;
#pragma unroll
      for (int mi = 0; mi < MF; ++mi)
#pragma unroll
        for (int ni = 0; ni < 4; ++ni) {
          int cl = wn * 64 + ni * 16 + l15;
#pragma unroll
          for (int reg = 0; reg < 4; ++reg) {
            float v = acc[mi][ni][reg] + bv[ni];
            if constexpr (EPI == 2) v = fast_gelu(v);
            Cs[(rbase + mi * 16 + reg) * CSTR + cl] = f2bf(v);
          }
        }
    }
    __syncthreads();
#pragma unroll
    for (int it = 0; it < BN / 32; ++it) {
      int idx = it * 512 + tid;
      int row = idx / (BN / 8);
      int c8 = (idx - row * (BN / 8)) * 8;
      int grow = m0 + cch * 128 + row;
      if (grow < M) {
        short8 val = *(const short8*)&Cs[row * CSTR + c8];
        u16* po = out + (size_t)grow * N + n0 + c8;
        if constexpr (EPI == 1) {
          short8 rv = *(const short8*)po;
          short8 gv = *(const short8*)(gamma + n0 + c8);
          short8 res;
#pragma unroll
          for (int e = 0; e < 8; ++e)
            res[e] = (short)f2bf(bf2f((u16)rv[e]) +
                                 bf2f((u16)gv[e]) * bf2f((u16)val[e]));
          *(short8*)po = res;
        } else {
          *(short8*)po = val;
        }
      }
    }
  }
}

// ---- window attention ------------------------------------------------------
__global__ __launch_bounds__(256) void attn_kernel(const u16* __restrict__ qkv,
                                                   const u16* __restrict__ btab,
                                                   u16* __restrict__ out) {
  __shared__ __align__(16) u16 VT[64 * 232];      // cols 196..223 zeroed
  __shared__ __align__(16) u16 Pa[4 * 2 * 512];   // per-wave double-buffered P
  __shared__ float bS[729];
  int bid = blockIdx.x;
  int win = bid / 12, h = bid - win * 12;
  int tid = threadIdx.x, w = tid >> 6, l = tid & 63;
  int lane15 = l & 15, quad = l >> 4;
  const u16* qbase = qkv + (size_t)win * 196 * 2304;

  for (int i = tid; i < 64 * 28; i += 256) {
    int d = i / 28, m = i - d * 28;
    VT[d * 232 + 196 + m] = 0;
  }
  for (int i = tid; i < 196 * 64; i += 256) {
    int m = i >> 6, d = i & 63;
    VT[d * 232 + m] = qbase[(size_t)m * 2304 + 1536 + h * 64 + d];
  }
  for (int i = tid; i < 729; i += 256) bS[i] = bf2f(btab[i * 12 + h]);
  __syncthreads();

  u16* Pw = Pa + w * 1024;
  for (int rt = w; rt < 13; rt += 4) {
    floatx4 acc[13];
#pragma unroll
    for (int nt = 0; nt < 13; ++nt)
#pragma unroll
      for (int e = 0; e < 4; ++e) acc[nt][e] = 0.f;

    int rq = rt * 16 + lane15;
    bool qok = rq < 196;
#pragma unroll
    for (int kk = 0; kk < 2; ++kk) {
      short8 qf;
      if (qok)
        qf = *(const short8*)&qbase[(size_t)rq * 2304 + h * 64 + kk * 32 + quad * 8];
      else
#pragma unroll
        for (int e = 0; e < 8; ++e) qf[e] = 0;
#pragma unroll
      for (int nt = 0; nt < 13; ++nt) {
        int n = nt * 16 + lane15;  // rows 196..207 over-read (allocated, masked)
        short8 kf = *(const short8*)&qbase[(size_t)n * 2304 + 768 + h * 64 + kk * 32 + quad * 8];
        acc[nt] = __builtin_amdgcn_mfma_f32_16x16x32_bf16(qf, kf, acc[nt], 0, 0, 0);
      }
    }

    int i1[4], j1[4]; bool rv[4]; float mx[4], sm[4];
#pragma unroll
    for (int reg = 0; reg < 4; ++reg) {
      int r = rt * 16 + quad * 4 + reg;
      i1[reg] = r / 14; j1[reg] = r - i1[reg] * 14;
      rv[reg] = r < 196; mx[reg] = -1e30f; sm[reg] = 0.f;
    }
#pragma unroll
    for (int nt = 0; nt < 13; ++nt) {
      int cc = nt * 16 + lane15;
      bool cv = cc < 196;
      int i2 = cc / 14, j2 = cc - i2 * 14;
#pragma unroll
      for (int reg = 0; reg < 4; ++reg) {
        float v;
        if (cv) {
          v = acc[nt][reg] * 0.125f;
          if (rv[reg]) v += bS[(i1[reg] - i2 + 13) * 27 + (j1[reg] - j2 + 13)];
        } else v = -1e30f;
        acc[nt][reg] = v;
        mx[reg] = fmaxf(mx[reg], v);
      }
    }
#pragma unroll
    for (int reg = 0; reg < 4; ++reg)
#pragma unroll
      for (int off = 1; off < 16; off <<= 1)
        mx[reg] = fmaxf(mx[reg], __shfl_xor(mx[reg], off));
#pragma unroll
    for (int nt = 0; nt < 13; ++nt)
#pragma unroll
      for (int reg = 0; reg < 4; ++reg) {
        float p = __expf(acc[nt][reg] - mx[reg]);
        acc[nt][reg] = p; sm[reg] += p;
      }
#pragma unroll
    for (int reg = 0; reg < 4; ++reg) {
#pragma unroll
      for (int off = 1; off < 16; off <<= 1) sm[reg] += __shfl_xor(sm[reg], off);
      sm[reg] = 1.f / sm[reg];
    }

    floatx4 oa[4];
#pragma unroll
    for (int dt = 0; dt < 4; ++dt)
#pragma unroll
      for (int e = 0; e < 4; ++e) oa[dt][e] = 0.f;
#pragma unroll
    for (int kk = 0; kk < 7; ++kk) {
      u16* Pb = Pw + (kk & 1) * 512;
#pragma unroll
      for (int p = 0; p < 2; ++p) {
        int nt = kk * 2 + p;
#pragma unroll
        for (int reg = 0; reg < 4; ++reg) {
          float v = (nt < 13) ? acc[nt][reg] * sm[reg] : 0.f;
          Pb[(quad * 4 + reg) * 32 + p * 16 + lane15] = f2bf(v);
        }
      }
      asm volatile("s_waitcnt lgkmcnt(0)" ::: "memory");
      short8 pf = *(const short8*)&Pb[lane15 * 32 + quad * 8];
#pragma unroll
      for (int dt = 0; dt < 4; ++dt) {
        short8 vf = *(const short8*)&VT[(dt * 16 + lane15) * 232 + kk * 32 + quad * 8];
        oa[dt] = __builtin_amdgcn_mfma_f32_16x16x32_bf16(pf, vf, oa[dt], 0, 0, 0);
      }
    }
#pragma unroll
    for (int dt = 0; dt < 4; ++dt)
#pragma unroll
      for (int reg = 0; reg < 4; ++reg) {
        int r = rt * 16 + quad * 4 + reg;
        if (r < 196)
          out[((size_t)win * 196 + r) * 768 + h * 64 + dt * 16 + lane15] =
              f2bf(oa[dt][reg]);
      }
  }
}

// ---------------------------------------------------------------------------
static inline int gemm_grid(int NX, int NYT) { return NX * ((NYT + 7) / 8) * 8; }

extern "C" void kernel_launch(void* const* d_in, const int* in_sizes, int n_in,
                              void* d_out, int out_size, void* d_ws, size_t ws_size,
                              hipStream_t stream) {
  const void* x      = d_in[0];
  const void* n1w    = d_in[1];
  const void* n1b    = d_in[2];
  const void* qkv_w  = d_in[3];
  const void* qkv_b  = d_in[4];
  const void* btab   = d_in[5];
  const void* proj_w = d_in[6];
  const void* proj_b = d_in[7];
  const void* n2w    = d_in[8];
  const void* n2b    = d_in[9];
  const void* fc1_w  = d_in[10];
  const void* fc1_b  = d_in[11];
  const void* fc2_w  = d_in[12];
  const void* fc2_b  = d_in[13];
  const void* gamma1 = d_in[14];
  const void* gamma2 = d_in[15];
  (void)in_sizes; (void)n_in; (void)out_size;

  int c;
  if      (ws_size >= 245432576ull) c = 1;
  else if (ws_size >= 168362240ull) c = 2;
  else                              c = 4;
  const int R = 25088 / c;
  const int WN = 128 / c;
  const int NYT = (R + 255) / 256;

  char* ws = (char*)d_ws;
  int*  flag  = (int*)ws;
  u16*  P     = (u16*)(ws + 256);
  u16*  qkvT  = (u16*)(ws + 65792);
  u16*  projT = (u16*)(ws + 65792 + 3538944);
  u16*  fc1T  = (u16*)(ws + 65792 + 4718592);
  u16*  fc2T  = (u16*)(ws + 65792 + 9437184);
  const size_t B0 = 38535168;
  u16*  buf0  = (u16*)(ws + 14221568);
  u16*  buf1  = (u16*)(ws + 14221568 + B0);
  char* scr   = ws + 14221568 + 2 * B0;

  u16 *p_n1w = P, *p_n1b = P + 768, *p_qkvb = P + 1536, *p_projb = P + 3840;
  u16 *p_n2w = P + 4608, *p_n2b = P + 5376, *p_fc1b = P + 6144;
  u16 *p_fc2b = P + 9216, *p_g1 = P + 9984, *p_g2 = P + 10752, *p_bt = P + 11520;

  dim3 b256(256), b512(512), bw(32, 8);
  detect_kernel<<<dim3(1), b256, 0, stream>>>((const u16*)x, flag);
  cvt_params_kernel<<<dim3(80), b256, 0, stream>>>(
      n1w, n1b, qkv_b, proj_b, n2w, n2b, fc1_b, fc2_b, gamma1, gamma2, btab,
      P, flag);
  wtr_kernel<<<dim3(72, 24), bw, 0, stream>>>(qkv_w, qkvT, 768, 2304, flag);
  wtr_kernel<<<dim3(24, 24), bw, 0, stream>>>(proj_w, projT, 768, 768, flag);
  wtr_kernel<<<dim3(96, 24), bw, 0, stream>>>(fc1_w, fc1T, 768, 3072, flag);
  wtr_kernel<<<dim3(24, 96), bw, 0, stream>>>(fc2_w, fc2T, 3072, 768, flag);

  tin_kernel<<<dim3(12, 56, 8), b256, 0, stream>>>(x, buf0, flag);
  ln_kernel<<<dim3(25088), b256, 0, stream>>>(buf0, p_n1w, p_n1b, buf1);

  for (int hc = 0; hc < c; ++hc) {
    size_t ro = (size_t)hc * R * 768;
    u16* qC = (u16*)scr;
    u16* aC = (u16*)(scr + (size_t)R * 4608);
    gemm256_kernel<0, 4><<<dim3(gemm_grid(9, NYT)), b512, 0, stream>>>(
        buf1 + ro, qkvT, p_qkvb, nullptr, qC, R, 2304, 768, 9, NYT);
    attn_kernel<<<dim3(WN * 12), b256, 0, stream>>>(qC, p_bt, aC);
    gemm256_kernel<1, 2><<<dim3(gemm_grid(6, NYT)), b512, 0, stream>>>(
        aC, projT, p_projb, p_g1, buf0 + ro, R, 768, 768, 6, NYT);
  }

  ln_kernel<<<dim3(25088), b256, 0, stream>>>(buf0, p_n2w, p_n2b, buf1);

  for (int hc = 0; hc < c; ++hc) {
    size_t ro = (size_t)hc * R * 768;
    u16* gC = (u16*)scr;
    gemm256_kernel<2, 4><<<dim3(gemm_grid(12, NYT)), b512, 0, stream>>>(
        buf1 + ro, fc1T, p_fc1b, nullptr, gC, R, 3072, 768, 12, NYT);
    gemm256_kernel<1, 2><<<dim3(gemm_grid(6, NYT)), b512, 0, stream>>>(
        gC, fc2T, p_fc2b, p_g2, buf0 + ro, R, 768, 3072, 6, NYT);
  }

  tout_kernel<<<dim3(12, 56, 8), b256, 0, stream>>>(buf0, d_out, flag);
}

// Round 4
// 963.165 us; speedup vs baseline: 1.0772x; 1.0345x over previous
//
#include <hip/hip_runtime.h>
#include <cstdint>
#include <cstddef>

// ---------------------------------------------------------------------------
// HiERABlock, MI355X.  Dtype-adaptive (fp32/bf16 inputs, flag sniffed on
// device).  Internal pipeline all bf16, "windowed row order".
// GEMMs: 256xBN-tile 8-wave BK=64 double-buffered pipeline:
//   T2 XOR-swizzled LDS (pre-swizzled global source for global_load_lds,
//   verified: SQ_LDS_BANK_CONFLICT == 0), T1 XCD blockIdx swizzle.
//   Round-4 schedule: ALL next-tile loads issued immediately after the
//   single per-tile {vmcnt(0); s_barrier} -- maximum latency cover with
//   depth-1 prefetch -- and NO intra-tile barriers (whole-tile dbuf means
//   no LDS hazard inside a tile), so the 2 waves/SIMD slip and overlap.
//   T5 setprio around the ds_read+MFMA region.
// LDS is STATIC __shared__ (128KB / 96KB).  No braced-init arrays of LDS
// pointers (clang folds those to unsupported static addrspacecast inits).
// BN=256 for qkv/fc1, BN=128 for N=768 GEMMs (proj/fc2) for dispatch-tail.
// EPI 0: bf16 out; EPI 1: layerscale residual RMW (coalesced); EPI 2: GELU.
// ---------------------------------------------------------------------------

typedef unsigned short u16;
typedef short short8 __attribute__((ext_vector_type(8)));
typedef float floatx4 __attribute__((ext_vector_type(4)));

static __device__ __forceinline__ float bf2f(u16 u) {
  return __uint_as_float(((unsigned)u) << 16);
}
static __device__ __forceinline__ u16 f2bf(float f) {
  unsigned u = __float_as_uint(f);
  return (u16)((u + 0x7FFFu + ((u >> 16) & 1u)) >> 16);
}
static __device__ __forceinline__ float ldin(const void* p, size_t i, int isf) {
  return isf ? ((const float*)p)[i] : bf2f(((const u16*)p)[i]);
}
static __device__ __forceinline__ void gload_lds16(const void* g, void* l) {
  __builtin_amdgcn_global_load_lds(
      (const __attribute__((address_space(1))) void*)g,
      (__attribute__((address_space(3))) void*)l, 16, 0, 0);
}
// tanh-form GELU: max |err| ~3e-4; downstream effect ~1e-9 (gamma2=1e-5)
static __device__ __forceinline__ float fast_gelu(float v) {
  float u2 = v * (1.5957691216f + 0.0713548163f * v * v);
  return v * (1.0f / (1.0f + __expf(-u2)));
}

// ---- dtype detector --------------------------------------------------------
__global__ __launch_bounds__(256) void detect_kernel(const u16* __restrict__ x,
                                                     int* __restrict__ flag) {
  __shared__ int tot;
  if (threadIdx.x == 0) tot = 0;
  __syncthreads();
  int cnt = 0;
  for (int i = threadIdx.x; i < 4096; i += 256) {
    int e = (x[i] >> 7) & 0xFF;
    if (e >= 0xC1) cnt++;
  }
  atomicAdd(&tot, cnt);
  __syncthreads();
  if (threadIdx.x == 0) flag[0] = (tot > 16) ? 1 : 0;
}

// ---- convert small params to bf16 ------------------------------------------
__global__ __launch_bounds__(256) void cvt_params_kernel(
    const void* n1w, const void* n1b, const void* qkvb, const void* projb,
    const void* n2w, const void* n2b, const void* fc1b, const void* fc2b,
    const void* g1, const void* g2, const void* bt, u16* __restrict__ P,
    const int* __restrict__ flag) {
  int isf = *flag;
  int i = blockIdx.x * 256 + threadIdx.x;
  const void* src; int off;
  if      (i < 768)   { src = n1w;   off = i; }
  else if (i < 1536)  { src = n1b;   off = i - 768; }
  else if (i < 3840)  { src = qkvb;  off = i - 1536; }
  else if (i < 4608)  { src = projb; off = i - 3840; }
  else if (i < 5376)  { src = n2w;   off = i - 4608; }
  else if (i < 6144)  { src = n2b;   off = i - 5376; }
  else if (i < 9216)  { src = fc1b;  off = i - 6144; }
  else if (i < 9984)  { src = fc2b;  off = i - 9216; }
  else if (i < 10752) { src = g1;    off = i - 9984; }
  else if (i < 11520) { src = g2;    off = i - 10752; }
  else if (i < 20268) { src = bt;    off = i - 11520; }
  else return;
  P[i] = f2bf(ldin(src, off, isf));
}

// ---- weight transpose ------------------------------------------------------
__global__ __launch_bounds__(256) void wtr_kernel(const void* __restrict__ W,
                                                  u16* __restrict__ WT,
                                                  int K, int N,
                                                  const int* __restrict__ flag) {
  int isf = *flag;
  __shared__ u16 tl[32][33];
  int tx = threadIdx.x, ty = threadIdx.y;
  int n0 = blockIdx.x * 32, k0 = blockIdx.y * 32;
#pragma unroll
  for (int j = 0; j < 32; j += 8)
    tl[ty + j][tx] = f2bf(ldin(W, (size_t)(k0 + ty + j) * N + n0 + tx, isf));
  __syncthreads();
#pragma unroll
  for (int j = 0; j < 32; j += 8)
    WT[(size_t)(n0 + ty + j) * K + k0 + tx] = tl[tx][ty + j];
}

// ---- input permute ---------------------------------------------------------
__global__ __launch_bounds__(256) void tin_kernel(const void* __restrict__ x,
                                                  u16* __restrict__ sc,
                                                  const int* __restrict__ flag) {
  int isf = *flag;
  int cc = blockIdx.x, h = blockIdx.y, b = blockIdx.z;  // grid (12,56,8)
  __shared__ u16 tile[64 * 57];
  int tid = threadIdx.x;
  for (int i = tid; i < 64 * 56; i += 256) {
    int ci = i / 56, w = i - ci * 56;
    tile[ci * 57 + w] =
        f2bf(ldin(x, (((size_t)b * 768 + cc * 64 + ci) * 56 + h) * 56 + w, isf));
  }
  __syncthreads();
  int hb = h / 14, hi = h - hb * 14;
  for (int i = tid; i < 56 * 64; i += 256) {
    int w = i >> 6, ci = i & 63;
    int wb = w / 14, wj = w - wb * 14;
    int r = (b * 16 + hb * 4 + wb) * 196 + hi * 14 + wj;
    sc[(size_t)r * 768 + cc * 64 + ci] = tile[ci * 57 + w];
  }
}

// ---- output permute --------------------------------------------------------
__global__ __launch_bounds__(256) void tout_kernel(const u16* __restrict__ src,
                                                   void* __restrict__ out,
                                                   const int* __restrict__ flag) {
  int isf = *flag;
  int cc = blockIdx.x, h = blockIdx.y, b = blockIdx.z;
  __shared__ u16 tile[64 * 57];
  int tid = threadIdx.x;
  int hb = h / 14, hi = h - hb * 14;
  for (int i = tid; i < 56 * 64; i += 256) {
    int w = i >> 6, ci = i & 63;
    int wb = w / 14, wj = w - wb * 14;
    int r = (b * 16 + hb * 4 + wb) * 196 + hi * 14 + wj;
    tile[ci * 57 + w] = src[(size_t)r * 768 + cc * 64 + ci];
  }
  __syncthreads();
  for (int i = tid; i < 64 * 56; i += 256) {
    int ci = i / 56, w = i - ci * 56;
    size_t o = (((size_t)b * 768 + cc * 64 + ci) * 56 + h) * 56 + w;
    if (isf) ((float*)out)[o] = bf2f(tile[ci * 57 + w]);
    else     ((u16*)out)[o]   = tile[ci * 57 + w];
  }
}

// ---- LayerNorm over C=768 --------------------------------------------------
__global__ __launch_bounds__(256) void ln_kernel(const u16* __restrict__ xin,
                                                 const u16* __restrict__ wt,
                                                 const u16* __restrict__ bs,
                                                 u16* __restrict__ out) {
  int row = blockIdx.x, t = threadIdx.x;
  const u16* xr = xin + (size_t)row * 768;
  float v0 = bf2f(xr[t]), v1 = bf2f(xr[t + 256]), v2 = bf2f(xr[t + 512]);
  float s1 = v0 + v1 + v2;
  float s2 = v0 * v0 + v1 * v1 + v2 * v2;
#pragma unroll
  for (int off = 32; off > 0; off >>= 1) {
    s1 += __shfl_xor(s1, off);
    s2 += __shfl_xor(s2, off);
  }
  __shared__ float p1[4], p2[4];
  if ((t & 63) == 0) { p1[t >> 6] = s1; p2[t >> 6] = s2; }
  __syncthreads();
  float S1 = p1[0] + p1[1] + p1[2] + p1[3];
  float S2 = p2[0] + p2[1] + p2[2] + p2[3];
  float mu = S1 * (1.f / 768.f);
  float var = S2 * (1.f / 768.f) - mu * mu;
  float rs = rsqrtf(var + 1e-5f);
  u16* orow = out + (size_t)row * 768;
  orow[t]       = f2bf((v0 - mu) * rs * bf2f(wt[t])       + bf2f(bs[t]));
  orow[t + 256] = f2bf((v1 - mu) * rs * bf2f(wt[t + 256]) + bf2f(bs[t + 256]));
  orow[t + 512] = f2bf((v2 - mu) * rs * bf2f(wt[t + 512]) + bf2f(bs[t + 512]));
}

// ---------------------------------------------------------------------------
// Pipelined 256xBN GEMM.  NPH=4 -> BN=256; NPH=2 -> BN=128.  BK=64.
// STATIC LDS (u16): A[2][256][64] then B[2][BN][64], XOR-swizzled:
//   physical 16B slot within a 128B row = logical_slot ^ (row & 7).
// Staging: global_load_lds writes linearly (base + lane*16B); the per-lane
// GLOBAL source address carries the inverse swizzle (rule #21).
// Main loop per K-tile t:
//   {vmcnt(0); s_barrier}            // own loads drained + all waves joined
//   issue ALL next-tile gloads       // earliest point buffer nxt is free
//   setprio(1); B-frags; 4x {A-frags; 16 MFMA}; setprio(0)
// NO intra-tile barriers: within a tile no LDS write touches the consumed
// buffer, so waves slip and MFMA of one wave hides the other's stalls.
// ---------------------------------------------------------------------------
template <int EPI, int NPH>
__global__ __launch_bounds__(512, 2) void gemm256_kernel(
    const u16* __restrict__ A, const u16* __restrict__ BT,
    const u16* __restrict__ bias, const u16* __restrict__ gamma,
    u16* __restrict__ out, int M, int N, int K, int NX, int NYT) {
  constexpr int BN  = 64 * NPH;      // 256 or 128
  constexpr int WM  = 8 / NPH;       // waves along M
  constexpr int MF  = 2 * NPH;       // m-fragments per wave
  constexpr int ATS = 16384;         // A K-tile size in u16 (256*64)
  constexpr int BTS = 4096 * NPH;    // B K-tile size in u16 (BN*64)
  __shared__ __align__(16) u16 LDS[2 * ATS + 2 * BTS];  // 128KB / 96KB static

  int bid = blockIdx.x;
  int r8 = bid & 7, q = bid >> 3;           // T1: XCD swizzle
  int xb = q % NX, yb = (q / NX) * 8 + r8;
  if (yb >= NYT) return;
  int m0 = yb * 256, n0 = xb * BN;

  int tid = threadIdx.x;
  int w = tid >> 6, l = tid & 63;
  int l15 = l & 15, quad = l >> 4;
  int wm = w & (WM - 1), wn = w / WM;

  // staging source pointers (pre-swizzled k offset)
  int lrow8 = l >> 3;                       // 0..7 = row within 8-row segment
  int lk = ((l & 7) ^ lrow8) * 8;           // swizzled k element offset
  const u16* aptr[4];
  const u16* bptr[NPH];
#pragma unroll
  for (int j = 0; j < 4; ++j) {
    int ra = m0 + w * 32 + j * 8 + lrow8;
    if (ra > M - 1) ra = M - 1;             // M-tail clamp (stores guarded)
    aptr[j] = A + (size_t)ra * K + lk;
  }
#pragma unroll
  for (int j = 0; j < NPH; ++j) {
    int rb = n0 + (w * NPH + j) * 8 + lrow8;
    bptr[j] = BT + (size_t)rb * K + lk;
  }
  // fragment-read swizzled in-row offsets (u16 units), kk = 0 / 1
  int kq0 = (((quad * 16)      ^ ((l15 & 7) << 4)) >> 1);
  int kq1 = (((64 + quad * 16) ^ ((l15 & 7) << 4)) >> 1);

  floatx4 acc[MF][4];
#pragma unroll
  for (int i = 0; i < MF; ++i)
#pragma unroll
    for (int jn = 0; jn < 4; ++jn)
#pragma unroll
      for (int e = 0; e < 4; ++e) acc[i][jn][e] = 0.f;

  int nt = K >> 6;
  // prologue: stage K-tile 0 into buffer 0
#pragma unroll
  for (int j = 0; j < 4; ++j)
    gload_lds16(aptr[j], LDS + (w * 4 + j) * 512);
#pragma unroll
  for (int j = 0; j < NPH; ++j)
    gload_lds16(bptr[j], LDS + 2 * ATS + (w * NPH + j) * 512);

  for (int t = 0; t < nt; ++t) {
    // double-buffer pointers computed per iteration (no LDS-ptr arrays!)
    int cur = t & 1, nxt = cur ^ 1;
    const u16* Ac = LDS + cur * ATS;
    const u16* Bc = LDS + 2 * ATS + cur * BTS;
    u16* An = LDS + nxt * ATS;
    u16* Bn = LDS + 2 * ATS + nxt * BTS;
    bool pf = (t + 1) < nt;
    int ko = (t + 1) << 6;
    // own loads for tile t drained, then join: all waves' tile-t data in LDS
    asm volatile("s_waitcnt vmcnt(0)" ::: "memory");
    __builtin_amdgcn_s_barrier();
    asm volatile("" ::: "memory");
    // issue ALL of tile t+1's loads now: full-tile latency cover, and they
    // stay in flight across the whole compute region below (no more waits
    // until the next tile boundary)
    if (pf) {
      if constexpr (NPH == 4) {
#pragma unroll
        for (int j = 0; j < 4; ++j) {
          gload_lds16(aptr[j] + ko, An + (w * 4 + j) * 512);
          gload_lds16(bptr[j] + ko, Bn + (w * 4 + j) * 512);
        }
      } else {
#pragma unroll
        for (int j = 0; j < 4; ++j)
          gload_lds16(aptr[j] + ko, An + (w * 4 + j) * 512);
#pragma unroll
        for (int j = 0; j < 2; ++j)
          gload_lds16(bptr[j] + ko, Bn + (w * 2 + j) * 512);
      }
    }
    __builtin_amdgcn_s_setprio(1);
    short8 bfr[4][2];
#pragma unroll
    for (int ni = 0; ni < 4; ++ni) {
      const u16* bp = Bc + (wn * 64 + ni * 16 + l15) * 64;
      bfr[ni][0] = *(const short8*)(bp + kq0);
      bfr[ni][1] = *(const short8*)(bp + kq1);
    }
#pragma unroll
    for (int p = 0; p < NPH; ++p) {
      short8 af0[2], af1[2];
      {
        const u16* ap0 = Ac + (wm * (32 * NPH) + (2 * p) * 16 + l15) * 64;
        const u16* ap1 = ap0 + 16 * 64;
        af0[0] = *(const short8*)(ap0 + kq0);
        af0[1] = *(const short8*)(ap0 + kq1);
        af1[0] = *(const short8*)(ap1 + kq0);
        af1[1] = *(const short8*)(ap1 + kq1);
      }
#pragma unroll
      for (int ni = 0; ni < 4; ++ni) {
        acc[2 * p][ni] = __builtin_amdgcn_mfma_f32_16x16x32_bf16(
            af0[0], bfr[ni][0], acc[2 * p][ni], 0, 0, 0);
        acc[2 * p][ni] = __builtin_amdgcn_mfma_f32_16x16x32_bf16(
            af0[1], bfr[ni][1], acc[2 * p][ni], 0, 0, 0);
        acc[2 * p + 1][ni] = __builtin_amdgcn_mfma_f32_16x16x32_bf16(
            af1[0], bfr[ni][0], acc[2 * p + 1][ni], 0, 0, 0);
        acc[2 * p + 1][ni] = __builtin_amdgcn_mfma_f32_16x16x32_bf16(
            af1[1], bfr[ni][1], acc[2 * p + 1][ni], 0, 0, 0);
      }
    }
    __builtin_amdgcn_s_setprio(0);
  }

  // ---- epilogue: repack C tile through LDS (aliases A/B buffers), coalesced
  constexpr int CSTR = BN + 8;
  u16* Cs = LDS;
  float bv[4];
#pragma unroll
  for (int ni = 0; ni < 4; ++ni)
    bv[ni] = bf2f(bias[n0 + wn * 64 + ni * 16 + l15]);
  for (int cch = 0; cch < 2; ++cch) {       // two 128-row chunks of the tile
    __syncthreads();
    if (((wm * NPH) >> 2) == cch) {
      int rbase = wm * (32 * NPH) - cch * 128 + quad * 4;
#pragma unroll
      for (int mi = 0; mi < MF; ++mi)
#pragma unroll
        for (int ni = 0; ni < 4; ++ni) {
          int cl = wn * 64 + ni * 16 + l15;
#pragma unroll
          for (int reg = 0; reg < 4; ++reg) {
            float v = acc[mi][ni][reg] + bv[ni];
            if constexpr (EPI == 2) v = fast_gelu(v);
            Cs[(rbase + mi * 16 + reg) * CSTR + cl] = f2bf(v);
          }
        }
    }
    __syncthreads();
#pragma unroll
    for (int it = 0; it < BN / 32; ++it) {
      int idx = it * 512 + tid;
      int row = idx / (BN / 8);
      int c8 = (idx - row * (BN / 8)) * 8;
      int grow = m0 + cch * 128 + row;
      if (grow < M) {
        short8 val = *(const short8*)&Cs[row * CSTR + c8];
        u16* po = out + (size_t)grow * N + n0 + c8;
        if constexpr (EPI == 1) {
          short8 rv = *(const short8*)po;
          short8 gv = *(const short8*)(gamma + n0 + c8);
          short8 res;
#pragma unroll
          for (int e = 0; e < 8; ++e)
            res[e] = (short)f2bf(bf2f((u16)rv[e]) +
                                 bf2f((u16)gv[e]) * bf2f((u16)val[e]));
          *(short8*)po = res;
        } else {
          *(short8*)po = val;
        }
      }
    }
  }
}

// ---- window attention ------------------------------------------------------
__global__ __launch_bounds__(256) void attn_kernel(const u16* __restrict__ qkv,
                                                   const u16* __restrict__ btab,
                                                   u16* __restrict__ out) {
  __shared__ __align__(16) u16 VT[64 * 232];      // cols 196..223 zeroed
  __shared__ __align__(16) u16 Pa[4 * 2 * 512];   // per-wave double-buffered P
  __shared__ float bS[729];
  int bid = blockIdx.x;
  int win = bid / 12, h = bid - win * 12;
  int tid = threadIdx.x, w = tid >> 6, l = tid & 63;
  int lane15 = l & 15, quad = l >> 4;
  const u16* qbase = qkv + (size_t)win * 196 * 2304;

  for (int i = tid; i < 64 * 28; i += 256) {
    int d = i / 28, m = i - d * 28;
    VT[d * 232 + 196 + m] = 0;
  }
  for (int i = tid; i < 196 * 64; i += 256) {
    int m = i >> 6, d = i & 63;
    VT[d * 232 + m] = qbase[(size_t)m * 2304 + 1536 + h * 64 + d];
  }
  for (int i = tid; i < 729; i += 256) bS[i] = bf2f(btab[i * 12 + h]);
  __syncthreads();

  u16* Pw = Pa + w * 1024;
  for (int rt = w; rt < 13; rt += 4) {
    floatx4 acc[13];
#pragma unroll
    for (int nt = 0; nt < 13; ++nt)
#pragma unroll
      for (int e = 0; e < 4; ++e) acc[nt][e] = 0.f;

    int rq = rt * 16 + lane15;
    bool qok = rq < 196;
#pragma unroll
    for (int kk = 0; kk < 2; ++kk) {
      short8 qf;
      if (qok)
        qf = *(const short8*)&qbase[(size_t)rq * 2304 + h * 64 + kk * 32 + quad * 8];
      else
#pragma unroll
        for (int e = 0; e < 8; ++e) qf[e] = 0;
#pragma unroll
      for (int nt = 0; nt < 13; ++nt) {
        int n = nt * 16 + lane15;  // rows 196..207 over-read (allocated, masked)
        short8 kf = *(const short8*)&qbase[(size_t)n * 2304 + 768 + h * 64 + kk * 32 + quad * 8];
        acc[nt] = __builtin_amdgcn_mfma_f32_16x16x32_bf16(qf, kf, acc[nt], 0, 0, 0);
      }
    }

    int i1[4], j1[4]; bool rv[4]; float mx[4], sm[4];
#pragma unroll
    for (int reg = 0; reg < 4; ++reg) {
      int r = rt * 16 + quad * 4 + reg;
      i1[reg] = r / 14; j1[reg] = r - i1[reg] * 14;
      rv[reg] = r < 196; mx[reg] = -1e30f; sm[reg] = 0.f;
    }
#pragma unroll
    for (int nt = 0; nt < 13; ++nt) {
      int cc = nt * 16 + lane15;
      bool cv = cc < 196;
      int i2 = cc / 14, j2 = cc - i2 * 14;
#pragma unroll
      for (int reg = 0; reg < 4; ++reg) {
        float v;
        if (cv) {
          v = acc[nt][reg] * 0.125f;
          if (rv[reg]) v += bS[(i1[reg] - i2 + 13) * 27 + (j1[reg] - j2 + 13)];
        } else v = -1e30f;
        acc[nt][reg] = v;
        mx[reg] = fmaxf(mx[reg], v);
      }
    }
#pragma unroll
    for (int reg = 0; reg < 4; ++reg)
#pragma unroll
      for (int off = 1; off < 16; off <<= 1)
        mx[reg] = fmaxf(mx[reg], __shfl_xor(mx[reg], off));
#pragma unroll
    for (int nt = 0; nt < 13; ++nt)
#pragma unroll
      for (int reg = 0; reg < 4; ++reg) {
        float p = __expf(acc[nt][reg] - mx[reg]);
        acc[nt][reg] = p; sm[reg] += p;
      }
#pragma unroll
    for (int reg = 0; reg < 4; ++reg) {
#pragma unroll
      for (int off = 1; off < 16; off <<= 1) sm[reg] += __shfl_xor(sm[reg], off);
      sm[reg] = 1.f / sm[reg];
    }

    floatx4 oa[4];
#pragma unroll
    for (int dt = 0; dt < 4; ++dt)
#pragma unroll
      for (int e = 0; e < 4; ++e) oa[dt][e] = 0.f;
#pragma unroll
    for (int kk = 0; kk < 7; ++kk) {
      u16* Pb = Pw + (kk & 1) * 512;
#pragma unroll
      for (int p = 0; p < 2; ++p) {
        int nt = kk * 2 + p;
#pragma unroll
        for (int reg = 0; reg < 4; ++reg) {
          float v = (nt < 13) ? acc[nt][reg] * sm[reg] : 0.f;
          Pb[(quad * 4 + reg) * 32 + p * 16 + lane15] = f2bf(v);
        }
      }
      asm volatile("s_waitcnt lgkmcnt(0)" ::: "memory");
      short8 pf = *(const short8*)&Pb[lane15 * 32 + quad * 8];
#pragma unroll
      for (int dt = 0; dt < 4; ++dt) {
        short8 vf = *(const short8*)&VT[(dt * 16 + lane15) * 232 + kk * 32 + quad * 8];
        oa[dt] = __builtin_amdgcn_mfma_f32_16x16x32_bf16(pf, vf, oa[dt], 0, 0, 0);
      }
    }
#pragma unroll
    for (int dt = 0; dt < 4; ++dt)
#pragma unroll
      for (int reg = 0; reg < 4; ++reg) {
        int r = rt * 16 + quad * 4 + reg;
        if (r < 196)
          out[((size_t)win * 196 + r) * 768 + h * 64 + dt * 16 + lane15] =
              f2bf(oa[dt][reg]);
      }
  }
}

// ---------------------------------------------------------------------------
static inline int gemm_grid(int NX, int NYT) { return NX * ((NYT + 7) / 8) * 8; }

extern "C" void kernel_launch(void* const* d_in, const int* in_sizes, int n_in,
                              void* d_out, int out_size, void* d_ws, size_t ws_size,
                              hipStream_t stream) {
  const void* x      = d_in[0];
  const void* n1w    = d_in[1];
  const void* n1b    = d_in[2];
  const void* qkv_w  = d_in[3];
  const void* qkv_b  = d_in[4];
  const void* btab   = d_in[5];
  const void* proj_w = d_in[6];
  const void* proj_b = d_in[7];
  const void* n2w    = d_in[8];
  const void* n2b    = d_in[9];
  const void* fc1_w  = d_in[10];
  const void* fc1_b  = d_in[11];
  const void* fc2_w  = d_in[12];
  const void* fc2_b  = d_in[13];
  const void* gamma1 = d_in[14];
  const void* gamma2 = d_in[15];
  (void)in_sizes; (void)n_in; (void)out_size;

  int c;
  if      (ws_size >= 245432576ull) c = 1;
  else if (ws_size >= 168362240ull) c = 2;
  else                              c = 4;
  const int R = 25088 / c;
  const int WN = 128 / c;
  const int NYT = (R + 255) / 256;

  char* ws = (char*)d_ws;
  int*  flag  = (int*)ws;
  u16*  P     = (u16*)(ws + 256);
  u16*  qkvT  = (u16*)(ws + 65792);
  u16*  projT = (u16*)(ws + 65792 + 3538944);
  u16*  fc1T  = (u16*)(ws + 65792 + 4718592);
  u16*  fc2T  = (u16*)(ws + 65792 + 9437184);
  const size_t B0 = 38535168;
  u16*  buf0  = (u16*)(ws + 14221568);
  u16*  buf1  = (u16*)(ws + 14221568 + B0);
  char* scr   = ws + 14221568 + 2 * B0;

  u16 *p_n1w = P, *p_n1b = P + 768, *p_qkvb = P + 1536, *p_projb = P + 3840;
  u16 *p_n2w = P + 4608, *p_n2b = P + 5376, *p_fc1b = P + 6144;
  u16 *p_fc2b = P + 9216, *p_g1 = P + 9984, *p_g2 = P + 10752, *p_bt = P + 11520;

  dim3 b256(256), b512(512), bw(32, 8);
  detect_kernel<<<dim3(1), b256, 0, stream>>>((const u16*)x, flag);
  cvt_params_kernel<<<dim3(80), b256, 0, stream>>>(
      n1w, n1b, qkv_b, proj_b, n2w, n2b, fc1_b, fc2_b, gamma1, gamma2, btab,
      P, flag);
  wtr_kernel<<<dim3(72, 24), bw, 0, stream>>>(qkv_w, qkvT, 768, 2304, flag);
  wtr_kernel<<<dim3(24, 24), bw, 0, stream>>>(proj_w, projT, 768, 768, flag);
  wtr_kernel<<<dim3(96, 24), bw, 0, stream>>>(fc1_w, fc1T, 768, 3072, flag);
  wtr_kernel<<<dim3(24, 96), bw, 0, stream>>>(fc2_w, fc2T, 3072, 768, flag);

  tin_kernel<<<dim3(12, 56, 8), b256, 0, stream>>>(x, buf0, flag);
  ln_kernel<<<dim3(25088), b256, 0, stream>>>(buf0, p_n1w, p_n1b, buf1);

  for (int hc = 0; hc < c; ++hc) {
    size_t ro = (size_t)hc * R * 768;
    u16* qC = (u16*)scr;
    u16* aC = (u16*)(scr + (size_t)R * 4608);
    gemm256_kernel<0, 4><<<dim3(gemm_grid(9, NYT)), b512, 0, stream>>>(
        buf1 + ro, qkvT, p_qkvb, nullptr, qC, R, 2304, 768, 9, NYT);
    attn_kernel<<<dim3(WN * 12), b256, 0, stream>>>(qC, p_bt, aC);
    gemm256_kernel<1, 2><<<dim3(gemm_grid(6, NYT)), b512, 0, stream>>>(
        aC, projT, p_projb, p_g1, buf0 + ro, R, 768, 768, 6, NYT);
  }

  ln_kernel<<<dim3(25088), b256, 0, stream>>>(buf0, p_n2w, p_n2b, buf1);

  for (int hc = 0; hc < c; ++hc) {
    size_t ro = (size_t)hc * R * 768;
    u16* gC = (u16*)scr;
    gemm256_kernel<2, 4><<<dim3(gemm_grid(12, NYT)), b512, 0, stream>>>(
        buf1 + ro, fc1T, p_fc1b, nullptr, gC, R, 3072, 768, 12, NYT);
    gemm256_kernel<1, 2><<<dim3(gemm_grid(6, NYT)), b512, 0, stream>>>(
        gC, fc2T, p_fc2b, p_g2, buf0 + ro, R, 768, 3072, 6, NYT);
  }

  tout_kernel<<<dim3(12, 56, 8), b256, 0, stream>>>(buf0, d_out, flag);
}